// Round 2
// baseline (814.683 us; speedup 1.0000x reference)
//
#include <hip/hip_runtime.h>
#include <hip/hip_bf16.h>

typedef _Float16 f16;
typedef _Float16 f16x4 __attribute__((ext_vector_type(4)));
typedef _Float16 f16x8 __attribute__((ext_vector_type(8)));
typedef float    f32x4 __attribute__((ext_vector_type(4)));

static __device__ __forceinline__ float bf2f(__hip_bfloat16 x) { return __bfloat162float(x); }
// dual-dtype float load/store: f32flag=1 -> float*, else bf16*
static __device__ __forceinline__ float ldf(const void* p, long i, int f32flag) {
    return f32flag ? ((const float*)p)[i] : bf2f(((const __hip_bfloat16*)p)[i]);
}
static __device__ __forceinline__ void stf(void* p, long i, int f32flag, float v) {
    if (f32flag) ((float*)p)[i] = v;
    else ((__hip_bfloat16*)p)[i] = __float2bfloat16(v);
}

// ---------------- workspace layout (bytes) ----------------
#define OFF_LOGITS 0L                               // S/logits: 32000 x 1024 f16
#define SZ_LOGITS  (32000L * 1024 * 2)
#define OFF_FEAT   (OFF_LOGITS + SZ_LOGITS)         // feat: 32000 x 768 f16
#define SZ_FEAT    (32000L * 768 * 2)
#define OFF_ATTF   (OFF_FEAT + SZ_FEAT)             // att_feat: 32000 x 768 f16
#define SZ_ATTF    (32000L * 768 * 2)
#define OFF_AWT    (OFF_ATTF + SZ_ATTF)             // attn_w^T: 999 x 768 f16
#define SZ_AWT     (999L * 768 * 2)
#define OFF_WCT    (OFF_AWT + SZ_AWT)               // Wc^T: 75 x 1536 f16
#define SZ_WCT     (75L * 1536 * 2)
#define OFF_BIAS   (OFF_WCT + SZ_WCT)               // f32[75] (padded 512)
#define OFF_FLAG   (OFF_BIAS + 512)                 // int flags[2]
#define OFF_FEATT  (OFF_FLAG + 64)                  // feat^T per batch: 32 x 768 x 1024 f16 (optional)
#define SZ_FEATT   (32L * 768 * 1024 * 2)
#define NEED_A     (OFF_FEATT + SZ_FEATT)           // ~216 MB
// without featT we only need OFF_FEATT (~166 MB)

// ---------------- detection: float dtype (flags[1]) + mask dtype (flags[0]) ----------------
// flags[0]: 0=int32, 1=int8/bool, 2=bf16, 3=int64, 4=f32   flags[1]: 1=f32 floats, 0=bf16 floats
__global__ void detect_kernel(const unsigned int* __restrict__ fv,
                              const unsigned int* __restrict__ m, int* __restrict__ flags)
{
    __shared__ int cnt, bits;
    int t = threadIdx.x;
    if (t == 0) { cnt = 0; bits = 0; }
    __syncthreads();
    // float dtype: fraction of halfwords that are plausible bf16 N(0,1) values
    int c = 0;
    for (int k = t; k < 2048; k += 256) {
        unsigned int w = fv[k];
        unsigned int h0 = w & 0xffffu, h1 = w >> 16;
        unsigned int e0 = (h0 >> 7) & 0xffu, e1 = (h1 >> 7) & 0xffu;
        c += (h0 == 0u || (e0 >= 100u && e0 <= 135u)) ? 1 : 0;
        c += (h1 == 0u || (e1 >= 100u && e1 <= 135u)) ? 1 : 0;
    }
    atomicAdd(&cnt, c);
    // mask dtype bits
    int lb = 0;
    for (int k = t; k < 192000; k += 256) {
        unsigned int w = m[k];
        if (w > 1u) lb |= 1;                        // some word not in {0,1}
        if ((k & 1) && w != 0u) lb |= 2;            // odd word nonzero
        unsigned int lo = w & 0xffffu, hi = w >> 16;
        if (!((lo == 0u || lo == 0x3f80u) && (hi == 0u || hi == 0x3f80u))) lb |= 4;
        if (lo == 0x3f80u) lb |= 8;
    }
    if (lb) atomicOr(&bits, lb);
    __syncthreads();
    if (t == 0) {
        int b = bits, f;
        if (!(b & 1))      f = (b & 2) ? 0 : 3;     // words all {0,1}: int32 vs int64
        else if (!(b & 4)) f = (b & 8) ? 2 : 4;     // {0,0x3f80} halves: bf16 vs f32
        else               f = 1;                    // raw bytes
        flags[0] = f;
        flags[1] = (cnt < 3900) ? 1 : 0;            // bf16 ~4096, f32 ~2335
    }
}

// ---------------- gather: build feat (f16) ----------------
__global__ __launch_bounds__(256) void build_feat_kernel(
    const void* __restrict__ fv, const int* __restrict__ x_idx,
    const void* __restrict__ maskp, const int* __restrict__ flags,
    f16* __restrict__ feat)
{
    int n = blockIdx.x, b = blockIdx.y;
    __shared__ int xs[12], ms[12], isf;
    int t = threadIdx.x;
    if (t == 0) isf = flags[1];
    if (t < 12) {
        long base = (long)n * 768 + t;              // (n*C + 0)*HF + h
        xs[t] = x_idx[base];
        int f = flags[0], mv;
        if (f == 0)      mv = ((const int*)maskp)[base] != 0;
        else if (f == 1) mv = ((const unsigned char*)maskp)[base] != 0;
        else if (f == 2) mv = ((const unsigned short*)maskp)[base] != 0;
        else if (f == 3) mv = ((const int*)maskp)[base * 2] != 0;
        else             mv = ((const unsigned int*)maskp)[base] != 0;
        ms[t] = mv;
    }
    __syncthreads();
    long ob = ((long)(b * 1000 + n)) * 768;
    int f32i = isf;
    #pragma unroll
    for (int r = 0; r < 3; r++) {
        int e = t + r * 256;
        int c = e / 12, h = e - c * 12;
        float v = ms[h] ? 0.f : ldf(fv, (((long)b * 64 + c) * 12 + h) * 20 + xs[h], f32i);
        feat[ob + e] = (f16)v;
    }
}

// ---------------- transpose into f16; SRC=1: dual-float input, SRC=0: f16 input ----------------
template<int SRC>
__global__ __launch_bounds__(256) void transpose_kernel(
    const void* __restrict__ inp, f16* __restrict__ out, const int* __restrict__ flags,
    int R, int C, int ldin, int ldout, long sIn, long sOut)
{
    __shared__ f16 tile[32][33];
    int isf = SRC ? flags[1] : 0;
    int c0 = blockIdx.x * 32, r0 = blockIdx.y * 32;
    int tx = threadIdx.x & 31, ty = threadIdx.x >> 5;
    #pragma unroll
    for (int i = ty; i < 32; i += 8) {
        int r = r0 + i, c = c0 + tx;
        float v = 0.f;
        if (r < R && c < C) {
            long idx = (long)blockIdx.z * sIn + (long)r * ldin + c;
            v = SRC ? ldf(inp, idx, isf) : (float)((const f16*)inp)[idx];
        }
        tile[i][tx] = (f16)v;
    }
    __syncthreads();
    #pragma unroll
    for (int i = ty; i < 32; i += 8) {
        int oc = c0 + i, orw = r0 + tx;
        if (oc < C && orw < R)
            out[(long)blockIdx.z * sOut + (long)oc * ldout + orw] = tile[tx][i];
    }
}

// ---------------- combined classifier/regressor weights ----------------
__global__ __launch_bounds__(256) void build_wc_kernel(
    const void* __restrict__ cls_w, const void* __restrict__ cls_b,
    const void* __restrict__ reg_w, const void* __restrict__ reg_b,
    const int* __restrict__ flags, f16* __restrict__ wcT, float* __restrict__ biasc)
{
    int isf = flags[1];
    int idx = blockIdx.x * 256 + threadIdx.x;       // 75*1536 = 115200 exactly
    if (idx < 75 * 1536) {
        int c = idx / 1536, k = idx - c * 1536;
        float v = (c < 2) ? ldf(cls_w, (long)k * 2 + c, isf)
                          : ldf(reg_w, (long)k * 73 + (c - 2), isf);
        wcT[idx] = (f16)v;                           // wcT[c][k], ld 1536
    }
    if (idx < 75)
        biasc[idx] = (idx < 2) ? ldf(cls_b, idx, isf) : ldf(reg_b, idx - 2, isf);
}

// ---------------- anchors passthrough (output cols 2,3) ----------------
__global__ __launch_bounds__(256) void anchors_fill_kernel(
    const void* __restrict__ anchors, const int* __restrict__ flags, void* __restrict__ out)
{
    int isf = flags[1];
    int idx = blockIdx.x * 256 + threadIdx.x;       // 64000 exactly
    int row = idx >> 1, c = 2 + (idx & 1);
    stf(out, (long)row * 77 + c, isf, ldf(anchors, (long)(row % 1000) * 77 + c, isf));
}

// ---------------- softmax over 999 + shifted scatter (in place) ----------------
__global__ __launch_bounds__(256) void softmax_kernel(
    f16* __restrict__ buf, const void* __restrict__ attn_b, const int* __restrict__ flags)
{
    int i = blockIdx.x, b = blockIdx.y;
    f16* row = buf + ((long)(b * 1000 + i)) * 1024;
    __shared__ float sv[999];
    __shared__ float redm[4], reds[4];
    int isf = flags[1];
    int t = threadIdx.x;
    float lmax = -3.4e38f;
    for (int k = t; k < 999; k += 256) {
        float v = (float)row[k] + ldf(attn_b, k, isf);
        sv[k] = v;
        lmax = fmaxf(lmax, v);
    }
    #pragma unroll
    for (int o = 32; o > 0; o >>= 1) lmax = fmaxf(lmax, __shfl_down(lmax, o, 64));
    if ((t & 63) == 0) redm[t >> 6] = lmax;
    __syncthreads();
    float gmax = fmaxf(fmaxf(redm[0], redm[1]), fmaxf(redm[2], redm[3]));
    float lsum = 0.f;
    for (int k = t; k < 999; k += 256) {
        float e = __expf(sv[k] - gmax);
        sv[k] = e;
        lsum += e;
    }
    #pragma unroll
    for (int o = 32; o > 0; o >>= 1) lsum += __shfl_down(lsum, o, 64);
    if ((t & 63) == 0) reds[t >> 6] = lsum;
    __syncthreads();
    float inv = 1.f / (reds[0] + reds[1] + reds[2] + reds[3]);
    for (int k = t; k < 999; k += 256) {
        int col = k + (k >= i ? 1 : 0);             // shift past diagonal
        row[col] = (f16)(sv[k] * inv);
    }
    if (t == 0) row[i] = (f16)0.f;                  // zero diagonal
}

// ---------------- MFMA GEMM: C = A @ B, B given as Bt (N x K) or K-major (K x N) ----------------
enum { OUT_F16 = 0, OUT_FINAL = 1 };

template<int MODE, bool CAT, bool BKM>
__global__ __launch_bounds__(256) void gemm_kernel(
    const f16* __restrict__ A, const f16* __restrict__ A2, int lda,
    const f16* __restrict__ Bt, int ldb,
    void* __restrict__ Cout, int ldc,
    int M, int Nc, int K,
    long sA, long sB, long sC,
    const float* __restrict__ bias, const void* __restrict__ anchors,
    const int* __restrict__ flags)
{
    __shared__ __align__(16) f16 As[128 * 40];
    __shared__ __align__(16) f16 Bs[BKM ? 32 * 132 : 128 * 40];
    int t = threadIdx.x;
    int m0 = blockIdx.y * 128, n0 = blockIdx.x * 128;
    int z = blockIdx.z;
    A  += (long)z * sA;
    if (CAT) A2 += (long)z * sA;
    Bt += (long)z * sB;
    int w = t >> 6, lane = t & 63;
    int wm = (w & 1) * 64, wn = (w >> 1) * 64;
    int lr = lane & 15, lq = lane >> 4;

    const f32x4 zero4 = {0.f, 0.f, 0.f, 0.f};
    const f16x8 zero8 = {(f16)0, (f16)0, (f16)0, (f16)0, (f16)0, (f16)0, (f16)0, (f16)0};
    const f16x4 zero4h = {(f16)0, (f16)0, (f16)0, (f16)0};
    f32x4 acc[4][4];
    #pragma unroll
    for (int i = 0; i < 4; i++)
        #pragma unroll
        for (int j = 0; j < 4; j++) acc[i][j] = zero4;

    for (int k0 = 0; k0 < K; k0 += 32) {
        const f16* Ak = A; int kk = k0;
        if (CAT && k0 >= 768) { Ak = A2; kk = k0 - 768; }
        __syncthreads();
        #pragma unroll
        for (int i = 0; i < 2; i++) {
            int q = t + i * 256;
            { // A tile: 128 rows x 32 k
                int row = q >> 2, kc = (q & 3) * 8;
                f16x8 av = zero8;
                if ((m0 + row) < M && (k0 + kc) < K)
                    av = *(const f16x8*)(Ak + (long)(m0 + row) * lda + kk + kc);
                *(f16x8*)&As[row * 40 + kc] = av;
            }
            if (!BKM) { // B^T tile: 128 n-rows x 32 k
                int row = q >> 2, kc = (q & 3) * 8;
                f16x8 bv = zero8;
                if ((n0 + row) < Nc && (k0 + kc) < K)
                    bv = *(const f16x8*)(Bt + (long)(n0 + row) * ldb + k0 + kc);
                *(f16x8*)&Bs[row * 40 + kc] = bv;
            } else {    // K-major B tile: 32 k-rows x 128 n
                int kr = q >> 4, nc = (q & 15) * 8;
                f16x4 b0 = zero4h, b1 = zero4h;
                if ((k0 + kr) < K && (n0 + nc) < Nc) {
                    const f16* p = Bt + (long)(k0 + kr) * ldb + n0 + nc;
                    b0 = *(const f16x4*)p;
                    b1 = *(const f16x4*)(p + 4);
                }
                *(f16x4*)&Bs[kr * 132 + nc]     = b0;
                *(f16x4*)&Bs[kr * 132 + nc + 4] = b1;
            }
        }
        __syncthreads();
        f16x8 af[4], bfr[4];
        #pragma unroll
        for (int i = 0; i < 4; i++)
            af[i] = *(const f16x8*)&As[(wm + i * 16 + lr) * 40 + lq * 8];
        if (!BKM) {
            #pragma unroll
            for (int j = 0; j < 4; j++)
                bfr[j] = *(const f16x8*)&Bs[(wn + j * 16 + lr) * 40 + lq * 8];
        } else {
            #pragma unroll
            for (int j = 0; j < 4; j++)
                #pragma unroll
                for (int jj = 0; jj < 8; jj++)
                    bfr[j][jj] = Bs[(lq * 8 + jj) * 132 + wn + j * 16 + lr];
        }
        #pragma unroll
        for (int i = 0; i < 4; i++)
            #pragma unroll
            for (int j = 0; j < 4; j++)
                acc[i][j] = __builtin_amdgcn_mfma_f32_16x16x32_f16(af[i], bfr[j], acc[i][j], 0, 0, 0);
    }

    int isf = (MODE == OUT_FINAL) ? flags[1] : 0;
    #pragma unroll
    for (int i = 0; i < 4; i++) {
        #pragma unroll
        for (int j = 0; j < 4; j++) {
            #pragma unroll
            for (int r = 0; r < 4; r++) {
                int gm = m0 + wm + i * 16 + lq * 4 + r;   // C/D: row = quad*4+reg
                int gn = n0 + wn + j * 16 + lr;           //      col = lane&15
                if (gm < M && gn < Nc) {
                    float v = acc[i][j][r];
                    if (MODE == OUT_F16) {
                        ((f16*)Cout)[(long)z * sC + (long)gm * ldc + gn] = (f16)v;
                    } else {
                        int oc = (gn < 2) ? gn : gn + 2;  // skip anchor cols 2,3
                        v += bias[gn];
                        if (gn >= 2) v += ldf(anchors, (long)(gm % 1000) * 77 + oc, isf);
                        stf(Cout, (long)gm * 77 + oc, isf, v);
                    }
                }
            }
        }
    }
}

extern "C" void kernel_launch(void* const* d_in, const int* in_sizes, int n_in,
                              void* d_out, int out_size, void* d_ws, size_t ws_size,
                              hipStream_t stream)
{
    const void* fv      = d_in[0];
    const void* attn_w  = d_in[1];
    const void* attn_b  = d_in[2];
    const void* cls_w   = d_in[3];
    const void* cls_b   = d_in[4];
    const void* reg_w   = d_in[5];
    const void* reg_b   = d_in[6];
    const void* anchors = d_in[7];
    const int*  x_idx   = (const int*)d_in[10];
    const void* maskp   = d_in[11];

    char* ws = (char*)d_ws;
    f16*   logits = (f16*)(ws + OFF_LOGITS);
    f16*   feat   = (f16*)(ws + OFF_FEAT);
    f16*   attf   = (f16*)(ws + OFF_ATTF);
    f16*   awT    = (f16*)(ws + OFF_AWT);
    f16*   wcT    = (f16*)(ws + OFF_WCT);
    float* biasc  = (float*)(ws + OFF_BIAS);
    int*   flags  = (int*)(ws + OFF_FLAG);
    f16*   featT  = (f16*)(ws + OFF_FEATT);
    bool bigws = ws_size >= (size_t)NEED_A;

    detect_kernel<<<dim3(1), dim3(256), 0, stream>>>(
        (const unsigned int*)fv, (const unsigned int*)maskp, flags);
    build_feat_kernel<<<dim3(1000, 32), dim3(256), 0, stream>>>(fv, x_idx, maskp, flags, feat);
    transpose_kernel<1><<<dim3(32, 24, 1), dim3(256), 0, stream>>>(
        attn_w, awT, flags, 768, 999, 999, 768, 0, 0);
    build_wc_kernel<<<dim3(450), dim3(256), 0, stream>>>(cls_w, cls_b, reg_w, reg_b, flags, wcT, biasc);
    anchors_fill_kernel<<<dim3(250), dim3(256), 0, stream>>>(anchors, flags, d_out);

    // GEMM1: logits = feat @ attn_w  (M=32000, N=999, K=768)
    gemm_kernel<OUT_F16, false, false><<<dim3(8, 250, 1), dim3(256), 0, stream>>>(
        feat, nullptr, 768, awT, 768, logits, 1024, 32000, 999, 768, 0, 0, 0,
        nullptr, nullptr, flags);
    softmax_kernel<<<dim3(1000, 32), dim3(256), 0, stream>>>(logits, attn_b, flags);
    // GEMM2 (batched): att_feat = S @ feat  (M=1000, N=768, K=1000, 32 batches)
    if (bigws) {
        transpose_kernel<0><<<dim3(24, 32, 32), dim3(256), 0, stream>>>(
            feat, featT, flags, 1000, 768, 768, 1024, 768000L, 786432L);
        gemm_kernel<OUT_F16, false, false><<<dim3(6, 8, 32), dim3(256), 0, stream>>>(
            logits, nullptr, 1024, featT, 1024, attf, 768, 1000, 768, 1000,
            1024000L, 786432L, 768000L, nullptr, nullptr, flags);
    } else {
        gemm_kernel<OUT_F16, false, true><<<dim3(6, 8, 32), dim3(256), 0, stream>>>(
            logits, nullptr, 1024, feat, 768, attf, 768, 1000, 768, 1000,
            1024000L, 768000L, 768000L, nullptr, nullptr, flags);
    }
    // GEMM3: out = [att_feat | feat] @ Wc + bias (+anchors), fused epilogue
    gemm_kernel<OUT_FINAL, true, false><<<dim3(1, 250, 1), dim3(256), 0, stream>>>(
        attf, feat, 768, wcT, 1536, d_out, 77, 32000, 75, 1536, 0, 0, 0,
        biasc, anchors, flags);
}

// Round 3
// 484.045 us; speedup vs baseline: 1.6831x; 1.6831x over previous
//
#include <hip/hip_runtime.h>
#include <hip/hip_bf16.h>

typedef _Float16 f16;
typedef _Float16 f16x4 __attribute__((ext_vector_type(4)));
typedef _Float16 f16x8 __attribute__((ext_vector_type(8)));
typedef float    f32x4 __attribute__((ext_vector_type(4)));

static __device__ __forceinline__ float bf2f(__hip_bfloat16 x) { return __bfloat162float(x); }
// dual-dtype float load/store: f32flag=1 -> float*, else bf16*
static __device__ __forceinline__ float ldf(const void* p, long i, int f32flag) {
    return f32flag ? ((const float*)p)[i] : bf2f(((const __hip_bfloat16*)p)[i]);
}
static __device__ __forceinline__ void stf(void* p, long i, int f32flag, float v) {
    if (f32flag) ((float*)p)[i] = v;
    else ((__hip_bfloat16*)p)[i] = __float2bfloat16(v);
}
// async global->LDS, 16B per lane; LDS dest is wave-uniform base + lane*16
static __device__ __forceinline__ void gl2lds16(const f16* g, f16* l) {
    __builtin_amdgcn_global_load_lds(
        (const __attribute__((address_space(1))) unsigned int*)(const void*)g,
        (__attribute__((address_space(3))) unsigned int*)(void*)l, 16, 0, 0);
}

// ---------------- workspace layout (bytes) ----------------
#define OFF_LOGITS 0L                               // S/logits: 32000 x 1024 f16
#define SZ_LOGITS  (32000L * 1024 * 2)
#define OFF_FEAT   (OFF_LOGITS + SZ_LOGITS)         // feat: 32000 x 768 f16
#define SZ_FEAT    (32000L * 768 * 2)
#define OFF_ATTF   (OFF_FEAT + SZ_FEAT)             // att_feat: 32000 x 768 f16
#define SZ_ATTF    (32000L * 768 * 2)
#define OFF_AWT    (OFF_ATTF + SZ_ATTF)             // attn_w^T: 1024 x 768 f16 (rows>=999 zero)
#define SZ_AWT     (1024L * 768 * 2)
#define OFF_WCT    (OFF_AWT + SZ_AWT)               // Wc^T: 128 x 1536 f16 (rows>=75 zero)
#define SZ_WCT     (128L * 1536 * 2)
#define OFF_BIAS   (OFF_WCT + SZ_WCT)               // f32[75] (padded 512)
#define OFF_FLAG   (OFF_BIAS + 512)                 // int flags[2]
#define OFF_FEATT  (OFF_FLAG + 64)                  // feat^T per batch: 32 x 768 x 1024 f16 (rows>=1000 zero)
#define SZ_FEATT   (32L * 768 * 1024 * 2)
#define NEED_A     (OFF_FEATT + SZ_FEATT)           // ~216 MB

// ---------------- detection (cheap sampling) ----------------
// flags[0]: 0=int32, 1=int8/bool, 2=bf16, 3=int64, 4=f32   flags[1]: 1=f32 floats, 0=bf16 floats
__global__ void detect_kernel(const unsigned int* __restrict__ fv,
                              const unsigned int* __restrict__ m,
                              int mwords, int* __restrict__ flags)
{
    __shared__ int cnt, bits;
    int t = threadIdx.x;
    if (t == 0) { cnt = 0; bits = 0; }
    __syncthreads();
    int c = 0;
    for (int k = t; k < 2048; k += 256) {
        unsigned int w = fv[k];
        unsigned int h0 = w & 0xffffu, h1 = w >> 16;
        unsigned int e0 = (h0 >> 7) & 0xffu, e1 = (h1 >> 7) & 0xffu;
        c += (h0 == 0u || (e0 >= 100u && e0 <= 135u)) ? 1 : 0;
        c += (h1 == 0u || (e1 >= 100u && e1 <= 135u)) ? 1 : 0;
    }
    atomicAdd(&cnt, c);
    int lb = 0;
    for (int k = t; k < mwords; k += 256) {
        unsigned int w = m[k];
        if (w > 1u) lb |= 1;                        // some word not in {0,1}
        if ((k & 1) && w != 0u) lb |= 2;            // odd word nonzero
        unsigned int lo = w & 0xffffu, hi = w >> 16;
        if (!((lo == 0u || lo == 0x3f80u) && (hi == 0u || hi == 0x3f80u))) lb |= 4;
        if (lo == 0x3f80u) lb |= 8;
    }
    if (lb) atomicOr(&bits, lb);
    __syncthreads();
    if (t == 0) {
        int b = bits, f;
        if (!(b & 1))      f = (b & 2) ? 0 : 3;     // words all {0,1}: int32 vs int64
        else if (!(b & 4)) f = (b & 8) ? 2 : 4;     // {0,0x3f80} halves: bf16 vs f32
        else               f = 1;                    // raw bytes
        flags[0] = f;
        flags[1] = (cnt < 3900) ? 1 : 0;            // bf16 ~4096 hits, f32 ~2335
    }
}

// ---------------- gather: build feat (f16), vec4 stores ----------------
__global__ __launch_bounds__(256) void build_feat_kernel(
    const void* __restrict__ fv, const int* __restrict__ x_idx,
    const void* __restrict__ maskp, const int* __restrict__ flags,
    int xstride, int mstride, f16* __restrict__ feat)
{
    int n = blockIdx.x, b = blockIdx.y;
    __shared__ int xs[12], ms[12], isf;
    int t = threadIdx.x;
    if (t == 0) isf = flags[1];
    if (t < 12) {
        xs[t] = x_idx[(long)n * xstride + t];
        long mb = (long)n * mstride + t;
        int f = flags[0], mv;
        if (f == 0)      mv = ((const int*)maskp)[mb] != 0;
        else if (f == 1) mv = ((const unsigned char*)maskp)[mb] != 0;
        else if (f == 2) mv = ((const unsigned short*)maskp)[mb] != 0;
        else if (f == 3) mv = ((const int*)maskp)[mb * 2] != 0;
        else             mv = ((const unsigned int*)maskp)[mb] != 0;
        ms[t] = mv;
    }
    __syncthreads();
    if (t >= 192) return;
    long ob = ((long)(b * 1000 + n)) * 768;
    int f32i = isf;
    int e0 = t * 4;
    f16x4 v4;
    #pragma unroll
    for (int j = 0; j < 4; j++) {
        int e = e0 + j;
        int c = e / 12, h = e - c * 12;
        float v = ms[h] ? 0.f : ldf(fv, (((long)b * 64 + c) * 12 + h) * 20 + xs[h], f32i);
        v4[j] = (f16)v;
    }
    *(f16x4*)(feat + ob + e0) = v4;
}

// ---------------- transpose into f16; SRC=1: dual-float input, SRC=0: f16 input ----------------
// reads guarded by (inR, inC), writes cover (R, C) with zero-fill outside
template<int SRC>
__global__ __launch_bounds__(256) void transpose_kernel(
    const void* __restrict__ inp, f16* __restrict__ out, const int* __restrict__ flags,
    int R, int C, int inR, int inC, int ldin, int ldout, long sIn, long sOut)
{
    __shared__ f16 tile[32][33];
    int isf = SRC ? flags[1] : 0;
    int c0 = blockIdx.x * 32, r0 = blockIdx.y * 32;
    int tx = threadIdx.x & 31, ty = threadIdx.x >> 5;
    #pragma unroll
    for (int i = ty; i < 32; i += 8) {
        int r = r0 + i, c = c0 + tx;
        float v = 0.f;
        if (r < inR && c < inC) {
            long idx = (long)blockIdx.z * sIn + (long)r * ldin + c;
            v = SRC ? ldf(inp, idx, isf) : (float)((const f16*)inp)[idx];
        }
        tile[i][tx] = (f16)v;
    }
    __syncthreads();
    #pragma unroll
    for (int i = ty; i < 32; i += 8) {
        int oc = c0 + i, orw = r0 + tx;
        if (oc < C && orw < R)
            out[(long)blockIdx.z * sOut + (long)oc * ldout + orw] = tile[tx][i];
    }
}

// ---------------- combined classifier/regressor weights (128 rows, zero-padded) ----------------
__global__ __launch_bounds__(256) void build_wc_kernel(
    const void* __restrict__ cls_w, const void* __restrict__ cls_b,
    const void* __restrict__ reg_w, const void* __restrict__ reg_b,
    const int* __restrict__ flags, f16* __restrict__ wcT, float* __restrict__ biasc)
{
    int isf = flags[1];
    int idx = blockIdx.x * 256 + threadIdx.x;       // 128*1536 = 196608
    if (idx < 128 * 1536) {
        int c = idx / 1536, k = idx - c * 1536;
        float v = 0.f;
        if (c < 2)       v = ldf(cls_w, (long)k * 2 + c, isf);
        else if (c < 75) v = ldf(reg_w, (long)k * 73 + (c - 2), isf);
        wcT[idx] = (f16)v;                           // wcT[c][k], ld 1536
    }
    if (idx < 75)
        biasc[idx] = (idx < 2) ? ldf(cls_b, idx, isf) : ldf(reg_b, idx - 2, isf);
}

// ---------------- softmax over 999 + shifted scatter (in place, register-resident) ----------------
__global__ __launch_bounds__(256) void softmax_kernel(
    f16* __restrict__ buf, const void* __restrict__ attn_b, const int* __restrict__ flags)
{
    int i = blockIdx.x, b = blockIdx.y;
    f16* row = buf + ((long)(b * 1000 + i)) * 1024;
    __shared__ float red[8];
    int isf = flags[1];
    int t = threadIdx.x;
    int k0 = t * 4;
    f16x4 rv = *(const f16x4*)(row + k0);            // all reads before any write
    float v[4];
    float lmax = -3.4e38f;
    #pragma unroll
    for (int j = 0; j < 4; j++) {
        int k = k0 + j;
        float x = (k < 999) ? (float)rv[j] + ldf(attn_b, k, isf) : -3.4e38f;
        v[j] = x;
        lmax = fmaxf(lmax, x);
    }
    #pragma unroll
    for (int o = 32; o > 0; o >>= 1) lmax = fmaxf(lmax, __shfl_down(lmax, o, 64));
    if ((t & 63) == 0) red[t >> 6] = lmax;
    __syncthreads();
    float gmax = fmaxf(fmaxf(red[0], red[1]), fmaxf(red[2], red[3]));
    float lsum = 0.f;
    #pragma unroll
    for (int j = 0; j < 4; j++) {
        int k = k0 + j;
        float e = (k < 999) ? __expf(v[j] - gmax) : 0.f;
        v[j] = e;
        lsum += e;
    }
    #pragma unroll
    for (int o = 32; o > 0; o >>= 1) lsum += __shfl_down(lsum, o, 64);
    if ((t & 63) == 0) red[4 + (t >> 6)] = lsum;
    __syncthreads();
    float inv = 1.f / (red[4] + red[5] + red[6] + red[7]);
    #pragma unroll
    for (int j = 0; j < 4; j++) {
        int k = k0 + j;
        if (k < 999) row[k + (k >= i ? 1 : 0)] = (f16)(v[j] * inv);
    }
    if (t == 0) row[i] = (f16)0.f;                   // zero diagonal
}

// ---------------- MFMA GEMM ----------------
// non-BKM: unguarded global_load_lds(16B) staging into XOR-swizzled unpadded LDS.
//   operands MUST be padded: M%128==0 reads (or slack rows inside ws), B rows padded
//   to n-tile, K%32==0. slot(row,chunk) = chunk ^ ((row>>1)&3): 2-way bank aliasing (free).
// BKM: legacy guarded VGPR staging, B read K-major (small-ws fallback).
enum { OUT_F16 = 0, OUT_FINAL = 1 };

template<int MODE, bool CAT, bool BKM>
__global__ __launch_bounds__(256) void gemm_kernel(
    const f16* __restrict__ A, const f16* __restrict__ A2, int lda,
    const f16* __restrict__ Bt, int ldb,
    void* __restrict__ Cout, int ldc,
    int M, int Nc, int K,
    long sA, long sB, long sC,
    const float* __restrict__ bias, const void* __restrict__ anchors,
    const int* __restrict__ flags)
{
    int t = threadIdx.x;
    int m0 = blockIdx.y * 128, n0 = blockIdx.x * 128;
    int z = blockIdx.z;
    A  += (long)z * sA;
    if (CAT) A2 += (long)z * sA;
    Bt += (long)z * sB;
    int w = t >> 6, lane = t & 63;
    int wm = (w & 1) * 64, wn = (w >> 1) * 64;
    int lr = lane & 15, lq = lane >> 4;

    const f32x4 zero4 = {0.f, 0.f, 0.f, 0.f};
    f32x4 acc[4][4];
    #pragma unroll
    for (int i = 0; i < 4; i++)
        #pragma unroll
        for (int j = 0; j < 4; j++) acc[i][j] = zero4;

    if constexpr (!BKM) {
        __shared__ __align__(16) f16 As[128 * 32];
        __shared__ __align__(16) f16 Bs[128 * 32];
        // staging geometry: q = t + i*256; row=q>>2, slot=q&3, global chunk = slot^((row>>1)&3)
        long aoff[2], boff[2];
        f16 *lA[2], *lB[2];
        #pragma unroll
        for (int i = 0; i < 2; i++) {
            int q = t + i * 256;
            int row = q >> 2, slot = q & 3;
            int c = slot ^ ((row >> 1) & 3);
            aoff[i] = (long)(m0 + row) * lda + c * 8;
            boff[i] = (long)(n0 + row) * ldb + c * 8;
            int ldsbase = (i * 256 + w * 64) * 8;    // wave-uniform (halves)
            lA[i] = &As[ldsbase];
            lB[i] = &Bs[ldsbase];
        }
        for (int k0 = 0; k0 < K; k0 += 32) {
            const f16* Ak = A; int kk = k0;
            if (CAT && k0 >= 768) { Ak = A2; kk = k0 - 768; }
            __syncthreads();
            #pragma unroll
            for (int i = 0; i < 2; i++) {
                gl2lds16(Ak + aoff[i] + kk, lA[i]);
                gl2lds16(Bt + boff[i] + k0, lB[i]);
            }
            __syncthreads();                         // drains vmcnt before barrier
            f16x8 af[4], bfr[4];
            #pragma unroll
            for (int i = 0; i < 4; i++) {
                int r = wm + i * 16 + lr;
                af[i] = *(const f16x8*)&As[r * 32 + (lq ^ ((r >> 1) & 3)) * 8];
            }
            #pragma unroll
            for (int j = 0; j < 4; j++) {
                int r = wn + j * 16 + lr;
                bfr[j] = *(const f16x8*)&Bs[r * 32 + (lq ^ ((r >> 1) & 3)) * 8];
            }
            #pragma unroll
            for (int i = 0; i < 4; i++)
                #pragma unroll
                for (int j = 0; j < 4; j++)
                    acc[i][j] = __builtin_amdgcn_mfma_f32_16x16x32_f16(af[i], bfr[j], acc[i][j], 0, 0, 0);
        }
    } else {
        __shared__ __align__(16) f16 As[128 * 40];
        __shared__ __align__(16) f16 Bs[32 * 132];
        const f16x8 zero8 = {(f16)0, (f16)0, (f16)0, (f16)0, (f16)0, (f16)0, (f16)0, (f16)0};
        const f16x4 zero4h = {(f16)0, (f16)0, (f16)0, (f16)0};
        for (int k0 = 0; k0 < K; k0 += 32) {
            __syncthreads();
            #pragma unroll
            for (int i = 0; i < 2; i++) {
                int q = t + i * 256;
                { int row = q >> 2, kc = (q & 3) * 8;
                  f16x8 av = zero8;
                  if ((m0 + row) < M && (k0 + kc) < K)
                      av = *(const f16x8*)(A + (long)(m0 + row) * lda + k0 + kc);
                  *(f16x8*)&As[row * 40 + kc] = av; }
                { int kr = q >> 4, nc = (q & 15) * 8;
                  f16x4 b0 = zero4h, b1 = zero4h;
                  if ((k0 + kr) < K && (n0 + nc) < Nc) {
                      const f16* p = Bt + (long)(k0 + kr) * ldb + n0 + nc;
                      b0 = *(const f16x4*)p;
                      b1 = *(const f16x4*)(p + 4);
                  }
                  *(f16x4*)&Bs[kr * 132 + nc]     = b0;
                  *(f16x4*)&Bs[kr * 132 + nc + 4] = b1; }
            }
            __syncthreads();
            f16x8 af[4], bfr[4];
            #pragma unroll
            for (int i = 0; i < 4; i++)
                af[i] = *(const f16x8*)&As[(wm + i * 16 + lr) * 40 + lq * 8];
            #pragma unroll
            for (int j = 0; j < 4; j++)
                #pragma unroll
                for (int jj = 0; jj < 8; jj++)
                    bfr[j][jj] = Bs[(lq * 8 + jj) * 132 + wn + j * 16 + lr];
            #pragma unroll
            for (int i = 0; i < 4; i++)
                #pragma unroll
                for (int j = 0; j < 4; j++)
                    acc[i][j] = __builtin_amdgcn_mfma_f32_16x16x32_f16(af[i], bfr[j], acc[i][j], 0, 0, 0);
        }
    }

    int isf = (MODE == OUT_FINAL) ? flags[1] : 0;
    #pragma unroll
    for (int i = 0; i < 4; i++) {
        #pragma unroll
        for (int j = 0; j < 4; j++) {
            #pragma unroll
            for (int r = 0; r < 4; r++) {
                int gm = m0 + wm + i * 16 + lq * 4 + r;   // C/D: row = quad*4+reg
                int gn = n0 + wn + j * 16 + lr;           //      col = lane&15
                if (MODE == OUT_F16) {
                    if (gm < M && gn < Nc)
                        ((f16*)Cout)[(long)z * sC + (long)gm * ldc + gn] = (f16)acc[i][j][r];
                } else {
                    if (gn < Nc) {                         // Nc=75 real cols
                        float v = acc[i][j][r] + bias[gn];
                        int oc = (gn < 2) ? gn : gn + 2;   // skip anchor cols 2,3
                        if (gn >= 2) v += ldf(anchors, (long)(gm % 1000) * 77 + oc, isf);
                        stf(Cout, (long)gm * 77 + oc, isf, v);
                    } else if (gn < 77) {                  // wasted lanes fill anchor cols 2,3
                        int oc = gn - 73;                  // 75->2, 76->3
                        stf(Cout, (long)gm * 77 + oc, isf,
                            ldf(anchors, (long)(gm % 1000) * 77 + oc, isf));
                    }
                }
            }
        }
    }
}

extern "C" void kernel_launch(void* const* d_in, const int* in_sizes, int n_in,
                              void* d_out, int out_size, void* d_ws, size_t ws_size,
                              hipStream_t stream)
{
    const void* fv      = d_in[0];
    const void* attn_w  = d_in[1];
    const void* attn_b  = d_in[2];
    const void* cls_w   = d_in[3];
    const void* cls_b   = d_in[4];
    const void* reg_w   = d_in[5];
    const void* reg_b   = d_in[6];
    const void* anchors = d_in[7];
    const int*  x_idx   = (const int*)d_in[10];
    const void* maskp   = d_in[11];
    int xstride = (in_sizes[10] < 768000) ? 12 : 768;   // un-broadcast fallback
    int mstride = (in_sizes[11] < 768000) ? 12 : 768;
    int mwords  = in_sizes[11] / 4;                      // int8 worst case, stay in bounds
    if (mwords > 4096) mwords = 4096;

    char* ws = (char*)d_ws;
    f16*   logits = (f16*)(ws + OFF_LOGITS);
    f16*   feat   = (f16*)(ws + OFF_FEAT);
    f16*   attf   = (f16*)(ws + OFF_ATTF);
    f16*   awT    = (f16*)(ws + OFF_AWT);
    f16*   wcT    = (f16*)(ws + OFF_WCT);
    float* biasc  = (float*)(ws + OFF_BIAS);
    int*   flags  = (int*)(ws + OFF_FLAG);
    f16*   featT  = (f16*)(ws + OFF_FEATT);
    bool bigws = ws_size >= (size_t)NEED_A;

    detect_kernel<<<dim3(1), dim3(256), 0, stream>>>(
        (const unsigned int*)fv, (const unsigned int*)maskp, mwords, flags);
    build_feat_kernel<<<dim3(1000, 32), dim3(256), 0, stream>>>(
        fv, x_idx, maskp, flags, xstride, mstride, feat);
    // attn_w (768 x 999) -> awT (1024 x 768), rows 999..1023 zero
    transpose_kernel<1><<<dim3(32, 24, 1), dim3(256), 0, stream>>>(
        attn_w, awT, flags, 768, 1024, 768, 999, 999, 768, 0, 0);
    build_wc_kernel<<<dim3(768), dim3(256), 0, stream>>>(
        cls_w, cls_b, reg_w, reg_b, flags, wcT, biasc);

    // GEMM1: logits = feat @ attn_w  (M=32000, N=1024 padded, K=768); cols>=999 come out 0
    gemm_kernel<OUT_F16, false, false><<<dim3(8, 250, 1), dim3(256), 0, stream>>>(
        feat, nullptr, 768, awT, 768, logits, 1024, 32000, 1024, 768, 0, 0, 0,
        nullptr, nullptr, flags);
    softmax_kernel<<<dim3(1000, 32), dim3(256), 0, stream>>>(logits, attn_b, flags);
    // GEMM2 (batched): att_feat = S @ feat  (M=1000, N=768, K=1024 padded, 32 batches)
    if (bigws) {
        // feat (1000 x 768 per batch) -> featT (768 x 1024 per batch), cols 1000..1023 zero
        transpose_kernel<0><<<dim3(24, 32, 32), dim3(256), 0, stream>>>(
            feat, featT, flags, 1024, 768, 1000, 768, 768, 1024, 768000L, 786432L);
        gemm_kernel<OUT_F16, false, false><<<dim3(6, 8, 32), dim3(256), 0, stream>>>(
            logits, nullptr, 1024, featT, 1024, attf, 768, 1000, 768, 1024,
            1024000L, 786432L, 768000L, nullptr, nullptr, flags);
    } else {
        gemm_kernel<OUT_F16, false, true><<<dim3(6, 8, 32), dim3(256), 0, stream>>>(
            logits, nullptr, 1024, feat, 768, attf, 768, 1000, 768, 1000,
            1024000L, 768000L, 768000L, nullptr, nullptr, flags);
    }
    // GEMM3: out = [att_feat | feat] @ Wc + bias (+anchors), fused epilogue + anchor cols
    gemm_kernel<OUT_FINAL, true, false><<<dim3(1, 250, 1), dim3(256), 0, stream>>>(
        attf, feat, 768, wcT, 1536, d_out, 77, 32000, 75, 1536, 0, 0, 0,
        biasc, anchors, flags);
}

// Round 4
// 458.811 us; speedup vs baseline: 1.7756x; 1.0550x over previous
//
#include <hip/hip_runtime.h>
#include <hip/hip_bf16.h>

typedef _Float16 f16;
typedef _Float16 f16x4 __attribute__((ext_vector_type(4)));
typedef _Float16 f16x8 __attribute__((ext_vector_type(8)));
typedef float    f32x4 __attribute__((ext_vector_type(4)));

static __device__ __forceinline__ float bf2f(__hip_bfloat16 x) { return __bfloat162float(x); }
// dual-dtype float load/store: f32flag=1 -> float*, else bf16*
static __device__ __forceinline__ float ldf(const void* p, long i, int f32flag) {
    return f32flag ? ((const float*)p)[i] : bf2f(((const __hip_bfloat16*)p)[i]);
}
static __device__ __forceinline__ void stf(void* p, long i, int f32flag, float v) {
    if (f32flag) ((float*)p)[i] = v;
    else ((__hip_bfloat16*)p)[i] = __float2bfloat16(v);
}
// async global->LDS, 16B per lane; LDS dest is wave-uniform base + lane*16
static __device__ __forceinline__ void gl2lds16(const f16* g, f16* l) {
    __builtin_amdgcn_global_load_lds(
        (const __attribute__((address_space(1))) unsigned int*)(const void*)g,
        (__attribute__((address_space(3))) unsigned int*)(void*)l, 16, 0, 0);
}

// ---------------- workspace layout (bytes) ----------------
#define OFF_LOGITS 0L                               // S/logits: 32000 x 1024 f16
#define SZ_LOGITS  (32000L * 1024 * 2)
#define OFF_FEAT   (OFF_LOGITS + SZ_LOGITS)         // feat: 32000 x 768 f16
#define SZ_FEAT    (32000L * 768 * 2)
#define OFF_ATTF   (OFF_FEAT + SZ_FEAT)             // att_feat: 32000 x 768 f16
#define SZ_ATTF    (32000L * 768 * 2)
#define OFF_AWT    (OFF_ATTF + SZ_ATTF)             // attn_w^T: 1024 x 768 f16 (rows>=999 zero)
#define SZ_AWT     (1024L * 768 * 2)
#define OFF_WCT    (OFF_AWT + SZ_AWT)               // Wc^T: 128 x 1536 f16 (rows>=75 zero)
#define SZ_WCT     (128L * 1536 * 2)
#define OFF_BIAS   (OFF_WCT + SZ_WCT)               // f32[75] (padded 512)
#define OFF_FLAG   (OFF_BIAS + 512)                 // int flags[2]
#define OFF_FEATT  (OFF_FLAG + 64)                  // feat^T per batch: 32 x 768 x 1024 f16
#define SZ_FEATT   (32L * 768 * 1024 * 2)
#define NEED_A     (OFF_FEATT + SZ_FEATT)           // ~216 MB

// ---------------- detection (cheap sampling) ----------------
// flags[0]: 0=int32, 1=int8/bool, 2=bf16, 3=int64, 4=f32   flags[1]: 1=f32 floats, 0=bf16 floats
__global__ void detect_kernel(const unsigned int* __restrict__ fv,
                              const unsigned int* __restrict__ m,
                              int mwords, int* __restrict__ flags)
{
    __shared__ int cnt, bits;
    int t = threadIdx.x;
    if (t == 0) { cnt = 0; bits = 0; }
    __syncthreads();
    int c = 0;
    for (int k = t; k < 2048; k += 256) {
        unsigned int w = fv[k];
        unsigned int h0 = w & 0xffffu, h1 = w >> 16;
        unsigned int e0 = (h0 >> 7) & 0xffu, e1 = (h1 >> 7) & 0xffu;
        c += (h0 == 0u || (e0 >= 100u && e0 <= 135u)) ? 1 : 0;
        c += (h1 == 0u || (e1 >= 100u && e1 <= 135u)) ? 1 : 0;
    }
    atomicAdd(&cnt, c);
    int lb = 0;
    for (int k = t; k < mwords; k += 256) {
        unsigned int w = m[k];
        if (w > 1u) lb |= 1;                        // some word not in {0,1}
        if ((k & 1) && w != 0u) lb |= 2;            // odd word nonzero
        unsigned int lo = w & 0xffffu, hi = w >> 16;
        if (!((lo == 0u || lo == 0x3f80u) && (hi == 0u || hi == 0x3f80u))) lb |= 4;
        if (lo == 0x3f80u) lb |= 8;
    }
    if (lb) atomicOr(&bits, lb);
    __syncthreads();
    if (t == 0) {
        int b = bits, f;
        if (!(b & 1))      f = (b & 2) ? 0 : 3;     // words all {0,1}: int32 vs int64
        else if (!(b & 4)) f = (b & 8) ? 2 : 4;     // {0,0x3f80} halves: bf16 vs f32
        else               f = 1;                    // raw bytes
        flags[0] = f;
        flags[1] = (cnt < 3900) ? 1 : 0;            // bf16 ~4096 hits, f32 ~2335
    }
}

// ---------------- gather: build feat via LDS-staged fv slab ----------------
// grid (8 n-chunks of 125, 32 batches); whole fv[b] (64x12x20) lives in LDS
__global__ __launch_bounds__(256) void build_feat_kernel(
    const void* __restrict__ fv, const int* __restrict__ x_idx,
    const void* __restrict__ maskp, const int* __restrict__ flags,
    int xstride, int mstride, f16* __restrict__ feat)
{
    __shared__ f16 sfv[15360];                      // [(c*12+h)*20 + x]
    __shared__ int sx[1500];                        // [n_local*12 + h]
    __shared__ unsigned char sm[1500];
    int b = blockIdx.y, n0 = blockIdx.x * 125;
    int t = threadIdx.x;
    int isf = flags[1], fm = flags[0];
    for (int k = t; k < 15360; k += 256)
        sfv[k] = (f16)ldf(fv, (long)b * 15360 + k, isf);
    for (int k = t; k < 1500; k += 256) {
        int n = k / 12, h = k - n * 12;
        sx[k] = x_idx[(long)(n0 + n) * xstride + h];
        long mb = (long)(n0 + n) * mstride + h;
        int mv;
        if (fm == 0)      mv = ((const int*)maskp)[mb] != 0;
        else if (fm == 1) mv = ((const unsigned char*)maskp)[mb] != 0;
        else if (fm == 2) mv = ((const unsigned short*)maskp)[mb] != 0;
        else if (fm == 3) mv = ((const int*)maskp)[mb * 2] != 0;
        else              mv = ((const unsigned int*)maskp)[mb] != 0;
        sm[k] = (unsigned char)mv;
    }
    __syncthreads();
    // 125 rows x 192 vec4-chunks = 24000 chunks
    for (int q = t; q < 24000; q += 256) {
        int n = q / 192, r = q - n * 192;
        int e0 = r * 4;
        f16x4 v;
        #pragma unroll
        for (int j = 0; j < 4; j++) {
            int e = e0 + j;
            int c = e / 12, h = e - c * 12;
            int kk = n * 12 + h;
            v[j] = sm[kk] ? (f16)0.f : sfv[(c * 12 + h) * 20 + sx[kk]];
        }
        *(f16x4*)(feat + ((long)(b * 1000 + n0 + n)) * 768 + e0) = v;
    }
}

// ---------------- transpose into f16; SRC=1: dual-float input, SRC=0: f16 input ----------------
template<int SRC>
__global__ __launch_bounds__(256) void transpose_kernel(
    const void* __restrict__ inp, f16* __restrict__ out, const int* __restrict__ flags,
    int R, int C, int inR, int inC, int ldin, int ldout, long sIn, long sOut)
{
    __shared__ f16 tile[32][33];
    int isf = SRC ? flags[1] : 0;
    int c0 = blockIdx.x * 32, r0 = blockIdx.y * 32;
    int tx = threadIdx.x & 31, ty = threadIdx.x >> 5;
    #pragma unroll
    for (int i = ty; i < 32; i += 8) {
        int r = r0 + i, c = c0 + tx;
        float v = 0.f;
        if (r < inR && c < inC) {
            long idx = (long)blockIdx.z * sIn + (long)r * ldin + c;
            v = SRC ? ldf(inp, idx, isf) : (float)((const f16*)inp)[idx];
        }
        tile[i][tx] = (f16)v;
    }
    __syncthreads();
    #pragma unroll
    for (int i = ty; i < 32; i += 8) {
        int oc = c0 + i, orw = r0 + tx;
        if (oc < C && orw < R)
            out[(long)blockIdx.z * sOut + (long)oc * ldout + orw] = tile[tx][i];
    }
}

// ---------------- combined classifier/regressor weights (128 rows, zero-padded) ----------------
__global__ __launch_bounds__(256) void build_wc_kernel(
    const void* __restrict__ cls_w, const void* __restrict__ cls_b,
    const void* __restrict__ reg_w, const void* __restrict__ reg_b,
    const int* __restrict__ flags, f16* __restrict__ wcT, float* __restrict__ biasc)
{
    int isf = flags[1];
    int idx = blockIdx.x * 256 + threadIdx.x;       // 128*1536 = 196608
    if (idx < 128 * 1536) {
        int c = idx / 1536, k = idx - c * 1536;
        float v = 0.f;
        if (c < 2)       v = ldf(cls_w, (long)k * 2 + c, isf);
        else if (c < 75) v = ldf(reg_w, (long)k * 73 + (c - 2), isf);
        wcT[idx] = (f16)v;                           // wcT[c][k], ld 1536
    }
    if (idx < 75)
        biasc[idx] = (idx < 2) ? ldf(cls_b, idx, isf) : ldf(reg_b, idx - 2, isf);
}

// ---------------- softmax over 999 + shifted scatter (in place, register-resident) ----------------
__global__ __launch_bounds__(256) void softmax_kernel(
    f16* __restrict__ buf, const void* __restrict__ attn_b, const int* __restrict__ flags)
{
    int i = blockIdx.x, b = blockIdx.y;
    f16* row = buf + ((long)(b * 1000 + i)) * 1024;
    __shared__ float red[8];
    int isf = flags[1];
    int t = threadIdx.x;
    int k0 = t * 4;
    f16x4 rv = *(const f16x4*)(row + k0);            // all reads before any write
    float v[4];
    float lmax = -3.4e38f;
    #pragma unroll
    for (int j = 0; j < 4; j++) {
        int k = k0 + j;
        float x = (k < 999) ? (float)rv[j] + ldf(attn_b, k, isf) : -3.4e38f;
        v[j] = x;
        lmax = fmaxf(lmax, x);
    }
    #pragma unroll
    for (int o = 32; o > 0; o >>= 1) lmax = fmaxf(lmax, __shfl_down(lmax, o, 64));
    if ((t & 63) == 0) red[t >> 6] = lmax;
    __syncthreads();
    float gmax = fmaxf(fmaxf(red[0], red[1]), fmaxf(red[2], red[3]));
    float lsum = 0.f;
    #pragma unroll
    for (int j = 0; j < 4; j++) {
        int k = k0 + j;
        float e = (k < 999) ? __expf(v[j] - gmax) : 0.f;
        v[j] = e;
        lsum += e;
    }
    #pragma unroll
    for (int o = 32; o > 0; o >>= 1) lsum += __shfl_down(lsum, o, 64);
    if ((t & 63) == 0) red[4 + (t >> 6)] = lsum;
    __syncthreads();
    float inv = 1.f / (red[4] + red[5] + red[6] + red[7]);
    #pragma unroll
    for (int j = 0; j < 4; j++) {
        int k = k0 + j;
        if (k < 999) row[k + (k >= i ? 1 : 0)] = (f16)(v[j] * inv);
    }
    if (t == 0) row[i] = (f16)0.f;                   // zero diagonal
}

// ---------------- MFMA GEMM ----------------
// non-BKM: unguarded global_load_lds(16B) staging into XOR-swizzled unpadded LDS.
// TM: m-tile (64 or 128), n-tile fixed 128. SWZ=1: GEMM2 batch->XCD locality remap.
enum { OUT_F16 = 0, OUT_FINAL = 1 };

template<int MODE, bool CAT, bool BKM, int TM, int SWZ>
__global__ __launch_bounds__(256) void gemm_kernel(
    const f16* __restrict__ A, const f16* __restrict__ A2, int lda,
    const f16* __restrict__ Bt, int ldb,
    void* __restrict__ Cout, int ldc,
    int M, int Nc, int K,
    long sA, long sB, long sC,
    const float* __restrict__ bias, const void* __restrict__ anchors,
    const int* __restrict__ flags)
{
    int t = threadIdx.x;
    int bx = blockIdx.x, by = blockIdx.y, bz = blockIdx.z;
    if constexpr (SWZ == 1) {                        // grid must be (6,8,32)
        int f = bx + 6 * by + 48 * bz;               // flat dispatch id
        int xcd = f & 7, j = f >> 3;                 // j in [0,192)
        int wix = j % 48;
        bz = xcd * 4 + j / 48;                       // 4 batches per XCD, sequential
        bx = wix % 6; by = wix / 6;
    }
    int m0 = by * TM, n0 = bx * 128;
    int z = bz;
    A  += (long)z * sA;
    if (CAT) A2 += (long)z * sA;
    Bt += (long)z * sB;
    int w = t >> 6, lane = t & 63;
    constexpr int NJ = (TM == 128) ? 4 : 2;
    int wm = (TM == 128) ? (w & 1) * 64 : 0;
    int wn = (TM == 128) ? (w >> 1) * 64 : w * 32;
    int lr = lane & 15, lq = lane >> 4;

    const f32x4 zero4 = {0.f, 0.f, 0.f, 0.f};
    f32x4 acc[4][NJ];
    #pragma unroll
    for (int i = 0; i < 4; i++)
        #pragma unroll
        for (int j = 0; j < NJ; j++) acc[i][j] = zero4;

    if constexpr (!BKM) {
        constexpr int AI = TM / 64;                  // A staging iterations
        __shared__ __align__(16) f16 As[TM * 32];
        __shared__ __align__(16) f16 Bs[128 * 32];
        long aoff[AI], boff[2];
        f16 *lA[AI], *lB[2];
        #pragma unroll
        for (int i = 0; i < AI; i++) {
            int q = t + i * 256;
            int row = q >> 2, slot = q & 3;
            int c = slot ^ ((row >> 1) & 3);
            aoff[i] = (long)(m0 + row) * lda + c * 8;
            lA[i] = &As[(i * 256 + w * 64) * 8];     // wave-uniform base
        }
        #pragma unroll
        for (int i = 0; i < 2; i++) {
            int q = t + i * 256;
            int row = q >> 2, slot = q & 3;
            int c = slot ^ ((row >> 1) & 3);
            boff[i] = (long)(n0 + row) * ldb + c * 8;
            lB[i] = &Bs[(i * 256 + w * 64) * 8];
        }
        for (int k0 = 0; k0 < K; k0 += 32) {
            const f16* Ak = A; int kk = k0;
            if (CAT && k0 >= 768) { Ak = A2; kk = k0 - 768; }
            __syncthreads();
            #pragma unroll
            for (int i = 0; i < AI; i++) gl2lds16(Ak + aoff[i] + kk, lA[i]);
            #pragma unroll
            for (int i = 0; i < 2;  i++) gl2lds16(Bt + boff[i] + k0, lB[i]);
            __syncthreads();                         // drains vmcnt before barrier
            f16x8 af[4], bfr[NJ];
            #pragma unroll
            for (int i = 0; i < 4; i++) {
                int r = wm + i * 16 + lr;
                af[i] = *(const f16x8*)&As[r * 32 + (lq ^ ((r >> 1) & 3)) * 8];
            }
            #pragma unroll
            for (int j = 0; j < NJ; j++) {
                int r = wn + j * 16 + lr;
                bfr[j] = *(const f16x8*)&Bs[r * 32 + (lq ^ ((r >> 1) & 3)) * 8];
            }
            #pragma unroll
            for (int i = 0; i < 4; i++)
                #pragma unroll
                for (int j = 0; j < NJ; j++)
                    acc[i][j] = __builtin_amdgcn_mfma_f32_16x16x32_f16(af[i], bfr[j], acc[i][j], 0, 0, 0);
        }
    } else {
        __shared__ __align__(16) f16 As[128 * 40];
        __shared__ __align__(16) f16 Bs[32 * 132];
        const f16x8 zero8 = {(f16)0, (f16)0, (f16)0, (f16)0, (f16)0, (f16)0, (f16)0, (f16)0};
        const f16x4 zero4h = {(f16)0, (f16)0, (f16)0, (f16)0};
        for (int k0 = 0; k0 < K; k0 += 32) {
            __syncthreads();
            #pragma unroll
            for (int i = 0; i < 2; i++) {
                int q = t + i * 256;
                { int row = q >> 2, kc = (q & 3) * 8;
                  f16x8 av = zero8;
                  if ((m0 + row) < M && (k0 + kc) < K)
                      av = *(const f16x8*)(A + (long)(m0 + row) * lda + k0 + kc);
                  *(f16x8*)&As[row * 40 + kc] = av; }
                { int kr = q >> 4, nc = (q & 15) * 8;
                  f16x4 b0 = zero4h, b1 = zero4h;
                  if ((k0 + kr) < K && (n0 + nc) < Nc) {
                      const f16* p = Bt + (long)(k0 + kr) * ldb + n0 + nc;
                      b0 = *(const f16x4*)p;
                      b1 = *(const f16x4*)(p + 4);
                  }
                  *(f16x4*)&Bs[kr * 132 + nc]     = b0;
                  *(f16x4*)&Bs[kr * 132 + nc + 4] = b1; }
            }
            __syncthreads();
            f16x8 af[4], bfr[4];
            #pragma unroll
            for (int i = 0; i < 4; i++)
                af[i] = *(const f16x8*)&As[(wm + i * 16 + lr) * 40 + lq * 8];
            #pragma unroll
            for (int j = 0; j < 4; j++)
                #pragma unroll
                for (int jj = 0; jj < 8; jj++)
                    bfr[j][jj] = Bs[(lq * 8 + jj) * 132 + wn + j * 16 + lr];
            #pragma unroll
            for (int i = 0; i < 4; i++)
                #pragma unroll
                for (int j = 0; j < 4; j++)
                    acc[i][j] = __builtin_amdgcn_mfma_f32_16x16x32_f16(af[i], bfr[j], acc[i][j], 0, 0, 0);
        }
    }

    int isf = (MODE == OUT_FINAL) ? flags[1] : 0;
    #pragma unroll
    for (int i = 0; i < 4; i++) {
        #pragma unroll
        for (int j = 0; j < NJ; j++) {
            #pragma unroll
            for (int r = 0; r < 4; r++) {
                int gm = m0 + wm + i * 16 + lq * 4 + r;   // C/D: row = quad*4+reg
                int gn = n0 + wn + j * 16 + lr;           //      col = lane&15
                if (MODE == OUT_F16) {
                    if (gm < M && gn < Nc)
                        ((f16*)Cout)[(long)z * sC + (long)gm * ldc + gn] = (f16)acc[i][j][r];
                } else {
                    if (gn < Nc) {                         // Nc=75 real cols
                        float v = acc[i][j][r] + bias[gn];
                        int oc = (gn < 2) ? gn : gn + 2;   // skip anchor cols 2,3
                        if (gn >= 2) v += ldf(anchors, (long)(gm % 1000) * 77 + oc, isf);
                        stf(Cout, (long)gm * 77 + oc, isf, v);
                    } else if (gn < 77) {                  // wasted lanes fill anchor cols 2,3
                        int oc = gn - 73;                  // 75->2, 76->3
                        stf(Cout, (long)gm * 77 + oc, isf,
                            ldf(anchors, (long)(gm % 1000) * 77 + oc, isf));
                    }
                }
            }
        }
    }
}

extern "C" void kernel_launch(void* const* d_in, const int* in_sizes, int n_in,
                              void* d_out, int out_size, void* d_ws, size_t ws_size,
                              hipStream_t stream)
{
    const void* fv      = d_in[0];
    const void* attn_w  = d_in[1];
    const void* attn_b  = d_in[2];
    const void* cls_w   = d_in[3];
    const void* cls_b   = d_in[4];
    const void* reg_w   = d_in[5];
    const void* reg_b   = d_in[6];
    const void* anchors = d_in[7];
    const int*  x_idx   = (const int*)d_in[10];
    const void* maskp   = d_in[11];
    int xstride = (in_sizes[10] < 768000) ? 12 : 768;   // un-broadcast fallback
    int mstride = (in_sizes[11] < 768000) ? 12 : 768;
    int mwords  = in_sizes[11] / 4;                      // int8 worst case, stay in bounds
    if (mwords > 4096) mwords = 4096;

    char* ws = (char*)d_ws;
    f16*   logits = (f16*)(ws + OFF_LOGITS);
    f16*   feat   = (f16*)(ws + OFF_FEAT);
    f16*   attf   = (f16*)(ws + OFF_ATTF);
    f16*   awT    = (f16*)(ws + OFF_AWT);
    f16*   wcT    = (f16*)(ws + OFF_WCT);
    float* biasc  = (float*)(ws + OFF_BIAS);
    int*   flags  = (int*)(ws + OFF_FLAG);
    f16*   featT  = (f16*)(ws + OFF_FEATT);
    bool bigws = ws_size >= (size_t)NEED_A;

    detect_kernel<<<dim3(1), dim3(256), 0, stream>>>(
        (const unsigned int*)fv, (const unsigned int*)maskp, mwords, flags);
    build_feat_kernel<<<dim3(8, 32), dim3(256), 0, stream>>>(
        fv, x_idx, maskp, flags, xstride, mstride, feat);
    // attn_w (768 x 999) -> awT (1024 x 768), rows 999..1023 zero
    transpose_kernel<1><<<dim3(32, 24, 1), dim3(256), 0, stream>>>(
        attn_w, awT, flags, 768, 1024, 768, 999, 999, 768, 0, 0);
    build_wc_kernel<<<dim3(768), dim3(256), 0, stream>>>(
        cls_w, cls_b, reg_w, reg_b, flags, wcT, biasc);

    // GEMM1: logits = feat @ attn_w  (M=32000, N=1024 padded, K=768)
    gemm_kernel<OUT_F16, false, false, 128, 0><<<dim3(8, 250, 1), dim3(256), 0, stream>>>(
        feat, nullptr, 768, awT, 768, logits, 1024, 32000, 1024, 768, 0, 0, 0,
        nullptr, nullptr, flags);
    softmax_kernel<<<dim3(1000, 32), dim3(256), 0, stream>>>(logits, attn_b, flags);
    // GEMM2 (batched): att_feat = S @ feat  (M=1000, N=768, K=1024 padded, 32 batches)
    if (bigws) {
        // feat (1000 x 768 per batch) -> featT (768 x 1024 per batch), cols 1000..1023 zero
        transpose_kernel<0><<<dim3(24, 32, 32), dim3(256), 0, stream>>>(
            feat, featT, flags, 1024, 768, 1000, 768, 768, 1024, 768000L, 786432L);
        gemm_kernel<OUT_F16, false, false, 128, 1><<<dim3(6, 8, 32), dim3(256), 0, stream>>>(
            logits, nullptr, 1024, featT, 1024, attf, 768, 1000, 768, 1024,
            1024000L, 786432L, 768000L, nullptr, nullptr, flags);
    } else {
        gemm_kernel<OUT_F16, false, true, 128, 0><<<dim3(6, 8, 32), dim3(256), 0, stream>>>(
            logits, nullptr, 1024, feat, 768, attf, 768, 1000, 768, 1000,
            1024000L, 768000L, 768000L, nullptr, nullptr, flags);
    }
    // GEMM3: out = [att_feat | feat] @ Wc, fused epilogue; TM=64 -> 500 blocks
    gemm_kernel<OUT_FINAL, true, false, 64, 0><<<dim3(1, 500, 1), dim3(256), 0, stream>>>(
        attf, feat, 768, wcT, 1536, d_out, 77, 32000, 75, 1536, 0, 0, 0,
        biasc, anchors, flags);
}

// Round 5
// 425.733 us; speedup vs baseline: 1.9136x; 1.0777x over previous
//
#include <hip/hip_runtime.h>
#include <hip/hip_bf16.h>

typedef _Float16 f16;
typedef _Float16 f16x4 __attribute__((ext_vector_type(4)));
typedef _Float16 f16x8 __attribute__((ext_vector_type(8)));
typedef float    f32x4 __attribute__((ext_vector_type(4)));

static __device__ __forceinline__ float bf2f(__hip_bfloat16 x) { return __bfloat162float(x); }
// dual-dtype float load/store: f32flag=1 -> float*, else bf16*
static __device__ __forceinline__ float ldf(const void* p, long i, int f32flag) {
    return f32flag ? ((const float*)p)[i] : bf2f(((const __hip_bfloat16*)p)[i]);
}
static __device__ __forceinline__ void stf(void* p, long i, int f32flag, float v) {
    if (f32flag) ((float*)p)[i] = v;
    else ((__hip_bfloat16*)p)[i] = __float2bfloat16(v);
}
// async global->LDS, 16B per lane; LDS dest is wave-uniform base + lane*16
static __device__ __forceinline__ void gl2lds16(const f16* g, f16* l) {
    __builtin_amdgcn_global_load_lds(
        (const __attribute__((address_space(1))) unsigned int*)(const void*)g,
        (__attribute__((address_space(3))) unsigned int*)(void*)l, 16, 0, 0);
}

// ---------------- workspace layout (bytes) ----------------
#define OFF_LOGITS 0L                               // S/logits: 32000 x 1024 f16
#define SZ_LOGITS  (32000L * 1024 * 2)
#define OFF_FEAT   (OFF_LOGITS + SZ_LOGITS)         // feat: 32000 x 768 f16
#define SZ_FEAT    (32000L * 768 * 2)
#define OFF_ATTF   (OFF_FEAT + SZ_FEAT)             // att_feat: 32000 x 768 f16
#define SZ_ATTF    (32000L * 768 * 2)
#define OFF_AWT    (OFF_ATTF + SZ_ATTF)             // attn_w^T: 1024 x 768 f16 (rows>=999 zero)
#define SZ_AWT     (1024L * 768 * 2)
#define OFF_WCT    (OFF_AWT + SZ_AWT)               // Wc^T: 128 x 1536 f16 (rows>=75 zero)
#define SZ_WCT     (128L * 1536 * 2)
#define OFF_BIAS   (OFF_WCT + SZ_WCT)               // f32[75] (padded 512)
#define OFF_FLAG   (OFF_BIAS + 512)                 // int flags[2]
#define OFF_FEATT  (OFF_FLAG + 64)                  // feat^T per batch: 32 x 768 x 1024 f16
#define SZ_FEATT   (32L * 768 * 1024 * 2)
#define NEED_A     (OFF_FEATT + SZ_FEATT)           // ~216 MB

// ---------------- detection (cheap sampling) ----------------
// flags[0]: 0=int32, 1=int8/bool, 2=bf16, 3=int64, 4=f32   flags[1]: 1=f32 floats, 0=bf16 floats
__global__ void detect_kernel(const unsigned int* __restrict__ fv,
                              const unsigned int* __restrict__ m,
                              int mwords, int* __restrict__ flags)
{
    __shared__ int cnt, bits;
    int t = threadIdx.x;
    if (t == 0) { cnt = 0; bits = 0; }
    __syncthreads();
    int c = 0;
    for (int k = t; k < 2048; k += 256) {
        unsigned int w = fv[k];
        unsigned int h0 = w & 0xffffu, h1 = w >> 16;
        unsigned int e0 = (h0 >> 7) & 0xffu, e1 = (h1 >> 7) & 0xffu;
        c += (h0 == 0u || (e0 >= 100u && e0 <= 135u)) ? 1 : 0;
        c += (h1 == 0u || (e1 >= 100u && e1 <= 135u)) ? 1 : 0;
    }
    atomicAdd(&cnt, c);
    int lb = 0;
    for (int k = t; k < mwords; k += 256) {
        unsigned int w = m[k];
        if (w > 1u) lb |= 1;                        // some word not in {0,1}
        if ((k & 1) && w != 0u) lb |= 2;            // odd word nonzero
        unsigned int lo = w & 0xffffu, hi = w >> 16;
        if (!((lo == 0u || lo == 0x3f80u) && (hi == 0u || hi == 0x3f80u))) lb |= 4;
        if (lo == 0x3f80u) lb |= 8;
    }
    if (lb) atomicOr(&bits, lb);
    __syncthreads();
    if (t == 0) {
        int b = bits, f;
        if (!(b & 1))      f = (b & 2) ? 0 : 3;     // words all {0,1}: int32 vs int64
        else if (!(b & 4)) f = (b & 8) ? 2 : 4;     // {0,0x3f80} halves: bf16 vs f32
        else               f = 1;                    // raw bytes
        flags[0] = f;
        flags[1] = (cnt < 3900) ? 1 : 0;            // bf16 ~4096 hits, f32 ~2335
    }
}

// ---------------- gather: build feat via LDS-staged fv slab ----------------
__global__ __launch_bounds__(256) void build_feat_kernel(
    const void* __restrict__ fv, const int* __restrict__ x_idx,
    const void* __restrict__ maskp, const int* __restrict__ flags,
    int xstride, int mstride, f16* __restrict__ feat)
{
    __shared__ f16 sfv[15360];                      // [(c*12+h)*20 + x]
    __shared__ int sx[1500];                        // [n_local*12 + h]
    __shared__ unsigned char sm[1500];
    int b = blockIdx.y, n0 = blockIdx.x * 125;
    int t = threadIdx.x;
    int isf = flags[1], fm = flags[0];
    for (int k = t; k < 15360; k += 256)
        sfv[k] = (f16)ldf(fv, (long)b * 15360 + k, isf);
    for (int k = t; k < 1500; k += 256) {
        int n = k / 12, h = k - n * 12;
        sx[k] = x_idx[(long)(n0 + n) * xstride + h];
        long mb = (long)(n0 + n) * mstride + h;
        int mv;
        if (fm == 0)      mv = ((const int*)maskp)[mb] != 0;
        else if (fm == 1) mv = ((const unsigned char*)maskp)[mb] != 0;
        else if (fm == 2) mv = ((const unsigned short*)maskp)[mb] != 0;
        else if (fm == 3) mv = ((const int*)maskp)[mb * 2] != 0;
        else              mv = ((const unsigned int*)maskp)[mb] != 0;
        sm[k] = (unsigned char)mv;
    }
    __syncthreads();
    for (int q = t; q < 24000; q += 256) {
        int n = q / 192, r = q - n * 192;
        int e0 = r * 4;
        f16x4 v;
        #pragma unroll
        for (int j = 0; j < 4; j++) {
            int e = e0 + j;
            int c = e / 12, h = e - c * 12;
            int kk = n * 12 + h;
            v[j] = sm[kk] ? (f16)0.f : sfv[(c * 12 + h) * 20 + sx[kk]];
        }
        *(f16x4*)(feat + ((long)(b * 1000 + n0 + n)) * 768 + e0) = v;
    }
}

// ---------------- transpose into f16; SRC=1: dual-float input, SRC=0: f16 input ----------------
template<int SRC>
__global__ __launch_bounds__(256) void transpose_kernel(
    const void* __restrict__ inp, f16* __restrict__ out, const int* __restrict__ flags,
    int R, int C, int inR, int inC, int ldin, int ldout, long sIn, long sOut)
{
    __shared__ f16 tile[32][33];
    int isf = SRC ? flags[1] : 0;
    int c0 = blockIdx.x * 32, r0 = blockIdx.y * 32;
    int tx = threadIdx.x & 31, ty = threadIdx.x >> 5;
    #pragma unroll
    for (int i = ty; i < 32; i += 8) {
        int r = r0 + i, c = c0 + tx;
        float v = 0.f;
        if (r < inR && c < inC) {
            long idx = (long)blockIdx.z * sIn + (long)r * ldin + c;
            v = SRC ? ldf(inp, idx, isf) : (float)((const f16*)inp)[idx];
        }
        tile[i][tx] = (f16)v;
    }
    __syncthreads();
    #pragma unroll
    for (int i = ty; i < 32; i += 8) {
        int oc = c0 + i, orw = r0 + tx;
        if (oc < C && orw < R)
            out[(long)blockIdx.z * sOut + (long)oc * ldout + orw] = tile[tx][i];
    }
}

// ---------------- combined classifier/regressor weights (128 rows, zero-padded) ----------------
__global__ __launch_bounds__(256) void build_wc_kernel(
    const void* __restrict__ cls_w, const void* __restrict__ cls_b,
    const void* __restrict__ reg_w, const void* __restrict__ reg_b,
    const int* __restrict__ flags, f16* __restrict__ wcT, float* __restrict__ biasc)
{
    int isf = flags[1];
    int idx = blockIdx.x * 256 + threadIdx.x;       // 128*1536 = 196608
    if (idx < 128 * 1536) {
        int c = idx / 1536, k = idx - c * 1536;
        float v = 0.f;
        if (c < 2)       v = ldf(cls_w, (long)k * 2 + c, isf);
        else if (c < 75) v = ldf(reg_w, (long)k * 73 + (c - 2), isf);
        wcT[idx] = (f16)v;                           // wcT[c][k], ld 1536
    }
    if (idx < 75)
        biasc[idx] = (idx < 2) ? ldf(cls_b, idx, isf) : ldf(reg_b, idx - 2, isf);
}

// ---------------- softmax over 999 + shifted scatter (in place, register-resident) ----------------
__global__ __launch_bounds__(256) void softmax_kernel(
    f16* __restrict__ buf, const void* __restrict__ attn_b, const int* __restrict__ flags)
{
    int i = blockIdx.x, b = blockIdx.y;
    f16* row = buf + ((long)(b * 1000 + i)) * 1024;
    __shared__ float red[8];
    int isf = flags[1];
    int t = threadIdx.x;
    int k0 = t * 4;
    f16x4 rv = *(const f16x4*)(row + k0);            // all reads before any write
    float v[4];
    float lmax = -3.4e38f;
    #pragma unroll
    for (int j = 0; j < 4; j++) {
        int k = k0 + j;
        float x = (k < 999) ? (float)rv[j] + ldf(attn_b, k, isf) : -3.4e38f;
        v[j] = x;
        lmax = fmaxf(lmax, x);
    }
    #pragma unroll
    for (int o = 32; o > 0; o >>= 1) lmax = fmaxf(lmax, __shfl_down(lmax, o, 64));
    if ((t & 63) == 0) red[t >> 6] = lmax;
    __syncthreads();
    float gmax = fmaxf(fmaxf(red[0], red[1]), fmaxf(red[2], red[3]));
    float lsum = 0.f;
    #pragma unroll
    for (int j = 0; j < 4; j++) {
        int k = k0 + j;
        float e = (k < 999) ? __expf(v[j] - gmax) : 0.f;
        v[j] = e;
        lsum += e;
    }
    #pragma unroll
    for (int o = 32; o > 0; o >>= 1) lsum += __shfl_down(lsum, o, 64);
    if ((t & 63) == 0) red[4 + (t >> 6)] = lsum;
    __syncthreads();
    float inv = 1.f / (red[4] + red[5] + red[6] + red[7]);
    #pragma unroll
    for (int j = 0; j < 4; j++) {
        int k = k0 + j;
        if (k < 999) row[k + (k >= i ? 1 : 0)] = (f16)(v[j] * inv);
    }
    if (t == 0) row[i] = (f16)0.f;                   // zero diagonal
}

// ---------------- MFMA GEMM ----------------
// non-BKM: unguarded global_load_lds(16B) staging into XOR-swizzled unpadded LDS.
// TM in {64,128}, TN in {128,256}. SWZ: 0 none; 2 GEMM1 m-group->XCD; 3 GEMM2 batch->XCD.
enum { OUT_F16 = 0, OUT_FINAL = 1 };

template<int MODE, bool CAT, bool BKM, int TM, int TN, int SWZ>
__global__ __launch_bounds__(256, 2) void gemm_kernel(
    const f16* __restrict__ A, const f16* __restrict__ A2, int lda,
    const f16* __restrict__ Bt, int ldb,
    void* __restrict__ Cout, int ldc,
    int M, int Nc, int K,
    long sA, long sB, long sC,
    const float* __restrict__ bias, const void* __restrict__ anchors,
    const int* __restrict__ flags)
{
    int t = threadIdx.x;
    int bx, by, bz;
    if constexpr (SWZ == 2) {          // grid 1024 flat: 250 m-groups x 4 n-blocks
        int bid = blockIdx.x;
        int xcd = bid & 7, s = bid >> 3;             // each XCD: groups g == xcd (mod 8)
        int g = xcd + 8 * (s >> 2);
        if (g >= 250) return;                        // 24 idle blocks
        by = g; bx = s & 3; bz = 0;
    } else if constexpr (SWZ == 3) {   // grid 768 flat: 8 XCD x 4 batches x 24 blocks
        int bid = blockIdx.x;
        int xcd = bid & 7, s = bid >> 3;             // s in [0,96)
        bz = xcd * 4 + s / 24;
        int wv = s % 24;
        by = wv / 3; bx = wv - by * 3;
    } else { bx = blockIdx.x; by = blockIdx.y; bz = blockIdx.z; }

    int m0 = by * TM, n0 = bx * TN;
    int z = bz;
    A  += (long)z * sA;
    if (CAT) A2 += (long)z * sA;
    Bt += (long)z * sB;
    int w = t >> 6, lane = t & 63;
    constexpr int NJ = (TN == 256) ? 8 : ((TM == 128) ? 4 : 2);
    int wm = (TM == 128) ? (w & 1) * 64 : 0;
    int wn = (TN == 256) ? (w >> 1) * 128 : ((TM == 128) ? (w >> 1) * 64 : w * 32);

    int lr = lane & 15, lq = lane >> 4;

    const f32x4 zero4 = {0.f, 0.f, 0.f, 0.f};
    f32x4 acc[4][NJ];
    #pragma unroll
    for (int i = 0; i < 4; i++)
        #pragma unroll
        for (int j = 0; j < NJ; j++) acc[i][j] = zero4;

    if constexpr (!BKM) {
        constexpr int AI = TM / 64;                  // A staging iterations
        constexpr int BI = TN / 64;                  // B staging iterations
        __shared__ __align__(16) f16 As[TM * 32];
        __shared__ __align__(16) f16 Bs[TN * 32];
        long aoff[AI], boff[BI];
        f16 *lA[AI], *lB[BI];
        #pragma unroll
        for (int i = 0; i < AI; i++) {
            int q = t + i * 256;
            int row = q >> 2, slot = q & 3;
            int c = slot ^ ((row >> 1) & 3);
            aoff[i] = (long)(m0 + row) * lda + c * 8;
            lA[i] = &As[(i * 256 + w * 64) * 8];     // wave-uniform base
        }
        #pragma unroll
        for (int i = 0; i < BI; i++) {
            int q = t + i * 256;
            int row = q >> 2, slot = q & 3;
            int c = slot ^ ((row >> 1) & 3);
            boff[i] = (long)(n0 + row) * ldb + c * 8;
            lB[i] = &Bs[(i * 256 + w * 64) * 8];
        }
        for (int k0 = 0; k0 < K; k0 += 32) {
            const f16* Ak = A; int kk = k0;
            if (CAT && k0 >= 768) { Ak = A2; kk = k0 - 768; }
            __syncthreads();
            #pragma unroll
            for (int i = 0; i < AI; i++) gl2lds16(Ak + aoff[i] + kk, lA[i]);
            #pragma unroll
            for (int i = 0; i < BI; i++) gl2lds16(Bt + boff[i] + k0, lB[i]);
            __syncthreads();                         // drains vmcnt before barrier
            f16x8 af[4], bfr[NJ];
            #pragma unroll
            for (int i = 0; i < 4; i++) {
                int r = wm + i * 16 + lr;
                af[i] = *(const f16x8*)&As[r * 32 + (lq ^ ((r >> 1) & 3)) * 8];
            }
            #pragma unroll
            for (int j = 0; j < NJ; j++) {
                int r = wn + j * 16 + lr;
                bfr[j] = *(const f16x8*)&Bs[r * 32 + (lq ^ ((r >> 1) & 3)) * 8];
            }
            #pragma unroll
            for (int i = 0; i < 4; i++)
                #pragma unroll
                for (int j = 0; j < NJ; j++)
                    acc[i][j] = __builtin_amdgcn_mfma_f32_16x16x32_f16(af[i], bfr[j], acc[i][j], 0, 0, 0);
        }
    } else {
        __shared__ __align__(16) f16 As[128 * 40];
        __shared__ __align__(16) f16 Bs[32 * 132];
        const f16x8 zero8 = {(f16)0, (f16)0, (f16)0, (f16)0, (f16)0, (f16)0, (f16)0, (f16)0};
        const f16x4 zero4h = {(f16)0, (f16)0, (f16)0, (f16)0};
        for (int k0 = 0; k0 < K; k0 += 32) {
            __syncthreads();
            #pragma unroll
            for (int i = 0; i < 2; i++) {
                int q = t + i * 256;
                { int row = q >> 2, kc = (q & 3) * 8;
                  f16x8 av = zero8;
                  if ((m0 + row) < M && (k0 + kc) < K)
                      av = *(const f16x8*)(A + (long)(m0 + row) * lda + k0 + kc);
                  *(f16x8*)&As[row * 40 + kc] = av; }
                { int kr = q >> 4, nc = (q & 15) * 8;
                  f16x4 b0 = zero4h, b1 = zero4h;
                  if ((k0 + kr) < K && (n0 + nc) < Nc) {
                      const f16* p = Bt + (long)(k0 + kr) * ldb + n0 + nc;
                      b0 = *(const f16x4*)p;
                      b1 = *(const f16x4*)(p + 4);
                  }
                  *(f16x4*)&Bs[kr * 132 + nc]     = b0;
                  *(f16x4*)&Bs[kr * 132 + nc + 4] = b1; }
            }
            __syncthreads();
            f16x8 af[4], bfr[NJ];
            #pragma unroll
            for (int i = 0; i < 4; i++)
                af[i] = *(const f16x8*)&As[(wm + i * 16 + lr) * 40 + lq * 8];
            #pragma unroll
            for (int j = 0; j < NJ; j++)
                #pragma unroll
                for (int jj = 0; jj < 8; jj++)
                    bfr[j][jj] = Bs[(lq * 8 + jj) * 132 + wn + j * 16 + lr];
            #pragma unroll
            for (int i = 0; i < 4; i++)
                #pragma unroll
                for (int j = 0; j < NJ; j++)
                    acc[i][j] = __builtin_amdgcn_mfma_f32_16x16x32_f16(af[i], bfr[j], acc[i][j], 0, 0, 0);
        }
    }

    int isf = (MODE == OUT_FINAL) ? flags[1] : 0;
    #pragma unroll
    for (int i = 0; i < 4; i++) {
        #pragma unroll
        for (int j = 0; j < NJ; j++) {
            #pragma unroll
            for (int r = 0; r < 4; r++) {
                int gm = m0 + wm + i * 16 + lq * 4 + r;   // C/D: row = quad*4+reg
                int gn = n0 + wn + j * 16 + lr;           //      col = lane&15
                if (MODE == OUT_F16) {
                    if (gm < M && gn < Nc)
                        ((f16*)Cout)[(long)z * sC + (long)gm * ldc + gn] = (f16)acc[i][j][r];
                } else {
                    if (gn < Nc) {                         // Nc=75 real cols
                        float v = acc[i][j][r] + bias[gn];
                        int oc = (gn < 2) ? gn : gn + 2;   // skip anchor cols 2,3
                        if (gn >= 2) v += ldf(anchors, (long)(gm % 1000) * 77 + oc, isf);
                        stf(Cout, (long)gm * 77 + oc, isf, v);
                    } else if (gn < 77) {                  // wasted lanes fill anchor cols 2,3
                        int oc = gn - 73;                  // 75->2, 76->3
                        stf(Cout, (long)gm * 77 + oc, isf,
                            ldf(anchors, (long)(gm % 1000) * 77 + oc, isf));
                    }
                }
            }
        }
    }
}

extern "C" void kernel_launch(void* const* d_in, const int* in_sizes, int n_in,
                              void* d_out, int out_size, void* d_ws, size_t ws_size,
                              hipStream_t stream)
{
    const void* fv      = d_in[0];
    const void* attn_w  = d_in[1];
    const void* attn_b  = d_in[2];
    const void* cls_w   = d_in[3];
    const void* cls_b   = d_in[4];
    const void* reg_w   = d_in[5];
    const void* reg_b   = d_in[6];
    const void* anchors = d_in[7];
    const int*  x_idx   = (const int*)d_in[10];
    const void* maskp   = d_in[11];
    int xstride = (in_sizes[10] < 768000) ? 12 : 768;   // un-broadcast fallback
    int mstride = (in_sizes[11] < 768000) ? 12 : 768;
    int mwords  = in_sizes[11] / 4;                      // int8 worst case, stay in bounds
    if (mwords > 4096) mwords = 4096;

    char* ws = (char*)d_ws;
    f16*   logits = (f16*)(ws + OFF_LOGITS);
    f16*   feat   = (f16*)(ws + OFF_FEAT);
    f16*   attf   = (f16*)(ws + OFF_ATTF);
    f16*   awT    = (f16*)(ws + OFF_AWT);
    f16*   wcT    = (f16*)(ws + OFF_WCT);
    float* biasc  = (float*)(ws + OFF_BIAS);
    int*   flags  = (int*)(ws + OFF_FLAG);
    f16*   featT  = (f16*)(ws + OFF_FEATT);
    bool bigws = ws_size >= (size_t)NEED_A;

    detect_kernel<<<dim3(1), dim3(256), 0, stream>>>(
        (const unsigned int*)fv, (const unsigned int*)maskp, mwords, flags);
    build_feat_kernel<<<dim3(8, 32), dim3(256), 0, stream>>>(
        fv, x_idx, maskp, flags, xstride, mstride, feat);
    // attn_w (768 x 999) -> awT (1024 x 768), rows 999..1023 zero
    transpose_kernel<1><<<dim3(32, 24, 1), dim3(256), 0, stream>>>(
        attn_w, awT, flags, 768, 1024, 768, 999, 999, 768, 0, 0);
    build_wc_kernel<<<dim3(768), dim3(256), 0, stream>>>(
        cls_w, cls_b, reg_w, reg_b, flags, wcT, biasc);

    // GEMM1: logits = feat @ attn_w  (M=32000, N=1024 padded, K=768)
    // TN=256, XCD-grouped: each m-group's 4 n-blocks on one XCD -> A-tile L2 reuse
    gemm_kernel<OUT_F16, false, false, 128, 256, 2><<<dim3(1024), dim3(256), 0, stream>>>(
        feat, nullptr, 768, awT, 768, logits, 1024, 32000, 1024, 768, 0, 0, 0,
        nullptr, nullptr, flags);
    softmax_kernel<<<dim3(1000, 32), dim3(256), 0, stream>>>(logits, attn_b, flags);
    // GEMM2 (batched): att_feat = S @ feat  (M=1000, N=768, K=1024 padded, 32 batches)
    if (bigws) {
        transpose_kernel<0><<<dim3(24, 32, 32), dim3(256), 0, stream>>>(
            feat, featT, flags, 1024, 768, 1000, 768, 768, 1024, 768000L, 786432L);
        gemm_kernel<OUT_F16, false, false, 128, 256, 3><<<dim3(768), dim3(256), 0, stream>>>(
            logits, nullptr, 1024, featT, 1024, attf, 768, 1000, 768, 1024,
            1024000L, 786432L, 768000L, nullptr, nullptr, flags);
    } else {
        gemm_kernel<OUT_F16, false, true, 128, 128, 0><<<dim3(6, 8, 32), dim3(256), 0, stream>>>(
            logits, nullptr, 1024, feat, 768, attf, 768, 1000, 768, 1000,
            1024000L, 768000L, 768000L, nullptr, nullptr, flags);
    }
    // GEMM3: out = [att_feat | feat] @ Wc, fused epilogue; TM=64 -> 500 blocks
    gemm_kernel<OUT_FINAL, true, false, 64, 128, 0><<<dim3(1, 500, 1), dim3(256), 0, stream>>>(
        attf, feat, 768, wcT, 1536, d_out, 77, 32000, 75, 1536, 0, 0, 0,
        biasc, anchors, flags);
}